// Round 1
// baseline (100.802 us; speedup 1.0000x reference)
//
#include <hip/hip_runtime.h>

#define N 512
#define D 512
#define TILE 32
#define DC 64      // d-chunk staged in LDS
#define PAD 68     // LDS row pitch in floats: breaks bank-stride, keeps 16B alignment

__device__ __forceinline__ void sl1(float& acc, float x, float y) {
    // SmoothL1(d), beta=1, scaled by 2: m*(2|d|-m), m=min(|d|,1). (x0.5 applied in epilogue)
    float d  = x - y;
    float ad = fabsf(d);
    float m  = fminf(ad, 1.0f);
    acc = fmaf(m, fmaf(2.0f, ad, -m), acc);
}

__global__ __launch_bounds__(64) void zero_kernel(float* sums, float* out) {
    if (threadIdx.x == 0) { sums[0] = 0.0f; sums[1] = 0.0f; out[0] = 0.0f; }
}

__global__ __launch_bounds__(256) void pair_sums_kernel(
    const float* __restrict__ Tm, const float* __restrict__ Sm,
    float* __restrict__ P, float* __restrict__ sums)
{
    const int mat = blockIdx.z;
    const float* __restrict__ X = mat ? Sm : Tm;
    float* __restrict__ Pm = P + (size_t)mat * (N * N);

    __shared__ float Xi[TILE][PAD];
    __shared__ float Xj[TILE][PAD];

    const int i0 = blockIdx.y * TILE;
    const int j0 = blockIdx.x * TILE;
    const int t  = threadIdx.x;
    const int tx = t & 15;
    const int ty = t >> 4;

    float a00 = 0.f, a01 = 0.f, a10 = 0.f, a11 = 0.f;

    for (int dc = 0; dc < D; dc += DC) {
        __syncthreads();   // protect LDS from previous iteration's readers
        #pragma unroll
        for (int k = 0; k < 2; ++k) {
            int idx = t + k * 256;          // 512 float4 per array, 2 per thread
            int row = idx >> 4;
            int c4  = (idx & 15) * 4;
            *(float4*)&Xi[row][c4] = *(const float4*)&X[(size_t)(i0 + row) * D + dc + c4];
            *(float4*)&Xj[row][c4] = *(const float4*)&X[(size_t)(j0 + row) * D + dc + c4];
        }
        __syncthreads();
        #pragma unroll 4
        for (int d4 = 0; d4 < DC / 4; ++d4) {
            float4 p0 = *(const float4*)&Xi[ty][d4 * 4];
            float4 p1 = *(const float4*)&Xi[ty + 16][d4 * 4];
            float4 q0 = *(const float4*)&Xj[tx][d4 * 4];
            float4 q1 = *(const float4*)&Xj[tx + 16][d4 * 4];
            sl1(a00, p0.x, q0.x); sl1(a00, p0.y, q0.y); sl1(a00, p0.z, q0.z); sl1(a00, p0.w, q0.w);
            sl1(a01, p0.x, q1.x); sl1(a01, p0.y, q1.y); sl1(a01, p0.z, q1.z); sl1(a01, p0.w, q1.w);
            sl1(a10, p1.x, q0.x); sl1(a10, p1.y, q0.y); sl1(a10, p1.z, q0.z); sl1(a10, p1.w, q0.w);
            sl1(a11, p1.x, q1.x); sl1(a11, p1.y, q1.y); sl1(a11, p1.z, q1.z); sl1(a11, p1.w, q1.w);
        }
    }

    float s00 = 0.5f * a00, s01 = 0.5f * a01, s10 = 0.5f * a10, s11 = 0.5f * a11;
    Pm[(size_t)(i0 + ty     ) * N + (j0 + tx     )] = s00;
    Pm[(size_t)(i0 + ty     ) * N + (j0 + tx + 16)] = s01;
    Pm[(size_t)(i0 + ty + 16) * N + (j0 + tx     )] = s10;
    Pm[(size_t)(i0 + ty + 16) * N + (j0 + tx + 16)] = s11;

    // block sum -> one atomic per block
    float bs = s00 + s01 + s10 + s11;
    #pragma unroll
    for (int off = 32; off > 0; off >>= 1) bs += __shfl_down(bs, off, 64);
    __shared__ float wpart[4];
    if ((t & 63) == 0) wpart[t >> 6] = bs;
    __syncthreads();
    if (t == 0) atomicAdd(&sums[mat], wpart[0] + wpart[1] + wpart[2] + wpart[3]);
}

__global__ __launch_bounds__(256) void final_kernel(
    const float* __restrict__ P, const float* __restrict__ sums, float* __restrict__ out)
{
    const float NN = (float)(N * N);
    const float cT = NN / sums[0];   // == 1/mean_T
    const float cS = NN / sums[1];
    float local = 0.0f;
    for (int p = blockIdx.x * 256 + threadIdx.x; p < N * N; p += gridDim.x * 256) {
        local += fabsf(P[p] * cT - P[N * N + p] * cS);
    }
    #pragma unroll
    for (int off = 32; off > 0; off >>= 1) local += __shfl_down(local, off, 64);
    __shared__ float wpart[4];
    if ((threadIdx.x & 63) == 0) wpart[threadIdx.x >> 6] = local;
    __syncthreads();
    if (threadIdx.x == 0) atomicAdd(out, wpart[0] + wpart[1] + wpart[2] + wpart[3]);
}

extern "C" void kernel_launch(void* const* d_in, const int* in_sizes, int n_in,
                              void* d_out, int out_size, void* d_ws, size_t ws_size,
                              hipStream_t stream) {
    const float* teacher = (const float*)d_in[0];
    const float* student = (const float*)d_in[1];
    float* out  = (float*)d_out;
    float* P    = (float*)d_ws;          // [2][N*N] pair sums (2 MB)
    float* sums = P + 2 * (size_t)N * N; // [2] global sums

    zero_kernel<<<1, 64, 0, stream>>>(sums, out);
    dim3 grid(N / TILE, N / TILE, 2);
    pair_sums_kernel<<<grid, 256, 0, stream>>>(teacher, student, P, sums);
    final_kernel<<<128, 256, 0, stream>>>(P, sums, out);
}

// Round 2
// 97.516 us; speedup vs baseline: 1.0337x; 1.0337x over previous
//
#include <hip/hip_runtime.h>

#define N 512
#define D 512
#define TILE 32
#define DC 64          // d-slice per block
#define PITCH 68       // LDS pitch (floats): 68 % 32 = 4 -> at most 2-way conflict (free); 16B-aligned
#define NT 16          // N/TILE
#define NTILES 136     // NT*(NT+1)/2 upper-triangular tiles
#define NSLICE 8       // D/DC

__device__ __forceinline__ void sl1(float& acc, float x, float y) {
    // 2*SmoothL1(d) = m*(2|d|-m), m=min(|d|,1); the 0.5 is applied in the epilogue
    float d  = x - y;
    float ad = fabsf(d);
    float m  = fminf(ad, 1.0f);
    acc = fmaf(m, fmaf(2.0f, ad, -m), acc);
}

__global__ __launch_bounds__(256, 8) void pair_sums_kernel(
    const float* __restrict__ Tm, const float* __restrict__ Sm,
    float* __restrict__ P, float* __restrict__ sums)
{
    // grid: x = NTILES (upper-tri tile id), y = NSLICE (d-slice), z = mat
    const int mat = blockIdx.z;
    const float* __restrict__ X = mat ? Sm : Tm;
    float* __restrict__ Pm = P + (size_t)mat * (N * N);

    // decode triangular tile index -> (ti, tj), ti <= tj (uniform scalar loop, <=16 iters)
    int rem = blockIdx.x, ti = 0;
    while (rem >= NT - ti) { rem -= NT - ti; ++ti; }
    const int tj = ti + rem;
    const int i0 = ti * TILE, j0 = tj * TILE;
    const int d0 = blockIdx.y * DC;

    __shared__ float Xi[TILE][PITCH];
    __shared__ float Xj[TILE][PITCH];

    const int t  = threadIdx.x;
    const int tx = t & 15;
    const int ty = t >> 4;

    // stage the 32x64 chunks (512 float4 per array, 2 per thread per array)
    #pragma unroll
    for (int kk = 0; kk < 2; ++kk) {
        int idx = t + kk * 256;
        int row = idx >> 4;            // 16 float4 per row
        int c4  = (idx & 15) * 4;
        *(float4*)&Xi[row][c4] = *(const float4*)&X[(size_t)(i0 + row) * D + d0 + c4];
        *(float4*)&Xj[row][c4] = *(const float4*)&X[(size_t)(j0 + row) * D + d0 + c4];
    }
    __syncthreads();   // the only barrier in the kernel

    float a00 = 0.f, a01 = 0.f, a10 = 0.f, a11 = 0.f;
    #pragma unroll 4
    for (int d4 = 0; d4 < DC / 4; ++d4) {
        float4 p0 = *(const float4*)&Xi[ty][d4 * 4];
        float4 p1 = *(const float4*)&Xi[ty + 16][d4 * 4];
        float4 q0 = *(const float4*)&Xj[tx][d4 * 4];
        float4 q1 = *(const float4*)&Xj[tx + 16][d4 * 4];
        sl1(a00, p0.x, q0.x); sl1(a00, p0.y, q0.y); sl1(a00, p0.z, q0.z); sl1(a00, p0.w, q0.w);
        sl1(a01, p0.x, q1.x); sl1(a01, p0.y, q1.y); sl1(a01, p0.z, q1.z); sl1(a01, p0.w, q1.w);
        sl1(a10, p1.x, q0.x); sl1(a10, p1.y, q0.y); sl1(a10, p1.z, q0.z); sl1(a10, p1.w, q0.w);
        sl1(a11, p1.x, q1.x); sl1(a11, p1.y, q1.y); sl1(a11, p1.z, q1.z); sl1(a11, p1.w, q1.w);
    }

    // masks: only store pairs with global i <= j
    const bool diag = (ti == tj);
    const bool w00 = !diag || (ty <= tx);   // (ty, tx)
    const bool w10 = !diag;                 // (ty+16, tx): on diag never i<=j
    // (ty, tx+16) on diag: ty<=15<16<=tx+16 -> always stored
    const float s00 = 0.5f * a00, s01 = 0.5f * a01, s10 = 0.5f * a10, s11 = 0.5f * a11;

    float bs = 0.f;
    if (w00) { atomicAdd(&Pm[(i0 + ty     ) * N + (j0 + tx     )], s00); bs += s00; }
              { atomicAdd(&Pm[(i0 + ty     ) * N + (j0 + tx + 16)], s01); bs += s01; }
    if (w10) { atomicAdd(&Pm[(i0 + ty + 16) * N + (j0 + tx     )], s10); bs += s10; }
    if (w00) { atomicAdd(&Pm[(i0 + ty + 16) * N + (j0 + tx + 16)], s11); bs += s11; }

    #pragma unroll
    for (int off = 32; off > 0; off >>= 1) bs += __shfl_down(bs, off, 64);
    __shared__ float wpart[4];
    if ((t & 63) == 0) wpart[t >> 6] = bs;
    __syncthreads();
    if (t == 0) atomicAdd(&sums[mat], wpart[0] + wpart[1] + wpart[2] + wpart[3]);
}

__global__ __launch_bounds__(256) void final_kernel(
    const float* __restrict__ P, const float* __restrict__ sums, float* __restrict__ out)
{
    const float NN = (float)N * (float)N;
    const float cT = NN / (2.0f * sums[0]);   // 1/mean_T (mean over all N^2 = 2*S_c/N^2)
    const float cS = NN / (2.0f * sums[1]);
    float local = 0.0f;
    const int nvec = N * N / 4;
    for (int v = blockIdx.x * 256 + threadIdx.x; v < nvec; v += gridDim.x * 256) {
        int i  = v >> 7;            // (v*4) / 512
        int jb = (v & 127) * 4;     // (v*4) % 512
        if (jb + 3 < i) continue;   // vector fully below diagonal: never written
        float4 tq = ((const float4*)P)[v];
        float4 sq = ((const float4*)(P + (size_t)N * N))[v];
        if (jb + 0 >= i) local += fabsf(tq.x * cT - sq.x * cS);
        if (jb + 1 >= i) local += fabsf(tq.y * cT - sq.y * cS);
        if (jb + 2 >= i) local += fabsf(tq.z * cT - sq.z * cS);
        if (jb + 3 >= i) local += fabsf(tq.w * cT - sq.w * cS);
    }
    #pragma unroll
    for (int off = 32; off > 0; off >>= 1) local += __shfl_down(local, off, 64);
    __shared__ float wpart[4];
    if ((threadIdx.x & 63) == 0) wpart[threadIdx.x >> 6] = local;
    __syncthreads();
    if (threadIdx.x == 0) atomicAdd(out, 2.0f * (wpart[0] + wpart[1] + wpart[2] + wpart[3]));
}

extern "C" void kernel_launch(void* const* d_in, const int* in_sizes, int n_in,
                              void* d_out, int out_size, void* d_ws, size_t ws_size,
                              hipStream_t stream) {
    const float* teacher = (const float*)d_in[0];
    const float* student = (const float*)d_in[1];
    float* out  = (float*)d_out;
    float* P    = (float*)d_ws;                   // [2][N*N] upper-tri pair sums (2 MB)
    float* sums = P + 2 * (size_t)N * N;          // [2] global sums

    // zero P + sums (atomically accumulated) and out via memset nodes
    hipMemsetAsync(d_ws, 0, (2 * (size_t)N * N + 2) * sizeof(float), stream);
    hipMemsetAsync(d_out, 0, sizeof(float), stream);

    dim3 grid(NTILES, NSLICE, 2);
    pair_sums_kernel<<<grid, 256, 0, stream>>>(teacher, student, P, sums);
    final_kernel<<<128, 256, 0, stream>>>(P, sums, out);
}